// Round 4
// baseline (300.177 us; speedup 1.0000x reference)
//
#include <hip/hip_runtime.h>

#define NROIS 128
#define OUTD  12
#define NVOX  (OUTD * OUTD * OUTD)
#define NCH   64
#define NKEYS (NROIS * NVOX)          // 221184 possible (roi,voxel) keys
#define RPB   64                      // rois per block (grid.y = 2)
#define FPF   12                      // full-param floats per roi

// Order-preserving encode of float32 into uint32 for atomicMax.
// f >= 0 -> bits | 0x80000000 ; f < 0 -> ~bits. Encoded real floats are > 0,
// so key==0 marks "empty" (and equals the bit pattern of +0.0f).
__device__ __forceinline__ unsigned enc_f32(float f) {
    unsigned b = __float_as_uint(f);
    return (b & 0x80000000u) ? ~b : (b | 0x80000000u);
}

__device__ __forceinline__ float dec_key(unsigned k) {
    unsigned b = (k & 0x80000000u) ? (k & 0x7fffffffu) : ~k;
    return __uint_as_float(b);
}

// ws layout
#define WS_FLAGS 16
#define WS_LIST  (WS_FLAGS + NKEYS * 4)
#define WS_REJ   (WS_LIST + NKEYS * 4)          // float4[NROIS]
#define WS_RAD2  (WS_REJ + NROIS * 16)          // float[NROIS]
#define WS_FULL  (WS_RAD2 + NROIS * 4)          // float[NROIS*FPF]

// Per-ROI precompute: exact reference-sequence params + conservative reject.
__global__ void roi_prep(const float* __restrict__ rois,
                         float4* __restrict__ rej, float* __restrict__ rad2,
                         float* __restrict__ full)
{
    int r = threadIdx.x;
    if (r >= NROIS) return;
    float cx = rois[7 * r + 0];
    float cy = rois[7 * r + 1];
    float cz = rois[7 * r + 2];
    float dx = rois[7 * r + 3];
    float dy = rois[7 * r + 4];
    float dz = rois[7 * r + 5];
    float nrz = -rois[7 * r + 6];
    float ca = cosf(nrz), sa = sinf(nrz);
    float hx = __fmul_rn(dx, 0.5f);
    float hy = __fmul_rn(dy, 0.5f);
    float hz = __fmul_rn(dz, 0.5f);
    float* F = full + r * FPF;
    F[0] = cx;  F[1] = cy;  F[2] = cz;
    F[3] = ca;  F[4] = sa;
    F[5] = hx;  F[6] = hy;  F[7] = hz;
    F[8]  = __fdiv_rn(dx, 12.0f);
    F[9]  = __fdiv_rn(dy, 12.0f);
    F[10] = __fdiv_rn(dz, 12.0f);
    F[11] = 0.0f;
    // Conservative superset reject: circle around (cx,cy) + z window.
    float R2 = 0.25f * (dx * dx + dy * dy);
    rad2[r] = R2 * 1.04f + 1e-4f;              // margin >> any fp rounding
    float zc = cz + hz;                         // z center of the box
    float zh = hz * 1.001f + 1e-3f;            // half-height + ~3mm margin
    rej[r] = make_float4(cx, cy, zc, zh);
}

// grid = (ceil(P/256), NROIS/RPB). Point in registers, ROI loop over LDS.
__global__ void __launch_bounds__(256) roi_pool_scatter(
        const float* __restrict__ pts,      // (P, 3)
        const float* __restrict__ feat,     // (P, 64)
        const float4* __restrict__ rej,
        const float* __restrict__ rad2,
        const float* __restrict__ full,
        unsigned*    __restrict__ out,      // (128, 1728, 64) encoded keys
        unsigned*    __restrict__ count,
        unsigned*    __restrict__ flags,
        unsigned*    __restrict__ list,
        int npts)
{
    __shared__ float4 sRej[RPB];
    __shared__ float  sRad[RPB];
    __shared__ float  sFull[RPB * FPF];
    int rbase = blockIdx.y * RPB;
    for (int i = threadIdx.x; i < RPB; i += blockDim.x) {
        sRej[i] = rej[rbase + i];
        sRad[i] = rad2[rbase + i];
    }
    for (int i = threadIdx.x; i < RPB * FPF; i += blockDim.x)
        sFull[i] = full[rbase * FPF + i];
    __syncthreads();

    int p = blockIdx.x * blockDim.x + threadIdx.x;
    if (p >= npts) return;

    float px = pts[3 * p + 0];
    float py = pts[3 * p + 1];
    float pz = pts[3 * p + 2];
    const float* fp = feat + (size_t)p * NCH;

    #pragma unroll 4
    for (int r = 0; r < RPB; ++r) {
        // --- cheap conservative reject (1 b128 + 1 b32 LDS read, ~8 VALU) ---
        float4 q = sRej[r];
        float sx = px - q.x;                // == __fsub_rn(px, cx)
        float sy = py - q.y;
        float d2 = sx * sx + sy * sy;       // contraction ok: margin absorbs
        bool maybe = (d2 < sRad[r]) && (fabsf(pz - q.z) <= q.w);
        if (!maybe) continue;

        // --- exact reference test (reference float32 op sequence) ---
        const float* F = &sFull[r * FPF];
        float sz = __fsub_rn(pz, F[2]);
        float ca = F[3], sa = F[4];
        float hx = F[5], hy = F[6], hz = F[7];
        float lx = __fsub_rn(__fmul_rn(sx, ca), __fmul_rn(sy, sa));
        float ly = __fadd_rn(__fmul_rn(sx, sa), __fmul_rn(sy, ca));

        bool in_box = (lx > -hx) && (lx < hx) &&
                      (ly > -hy) && (ly < hy) &&
                      (fabsf(__fsub_rn(sz, hz)) <= hz);
        if (!in_box) continue;

        int xi = (int)floorf(__fdiv_rn(__fadd_rn(lx, hx), F[8]));
        int yi = (int)floorf(__fdiv_rn(__fadd_rn(ly, hy), F[9]));
        int zi = (int)floorf(__fdiv_rn(sz,                F[10]));
        xi = min(max(xi, 0), OUTD - 1);
        yi = min(max(yi, 0), OUTD - 1);
        zi = min(max(zi, 0), OUTD - 1);

        int key = (rbase + r) * NVOX + xi * (OUTD * OUTD) + yi * OUTD + zi;

        // First toucher registers this (roi,voxel) for the decode pass.
        if (atomicExch(&flags[key], 1u) == 0u) {
            unsigned idx = atomicAdd(count, 1u);
            list[idx] = (unsigned)key;
        }

        unsigned* dst = out + (size_t)key * NCH;
        #pragma unroll
        for (int c = 0; c < NCH; c += 4) {
            float4 v = *reinterpret_cast<const float4*>(fp + c);
            atomicMax(dst + c + 0, enc_f32(v.x));
            atomicMax(dst + c + 1, enc_f32(v.y));
            atomicMax(dst + c + 2, enc_f32(v.z));
            atomicMax(dst + c + 3, enc_f32(v.w));
        }
    }
}

// Grid-stride over the touched-voxel list; one wave per entry, lane = channel.
__global__ void __launch_bounds__(256) decode_touched(
        unsigned* __restrict__ out,
        const unsigned* __restrict__ count,
        const unsigned* __restrict__ list)
{
    int wid  = (blockIdx.x * blockDim.x + threadIdx.x) >> 6;
    int lane = threadIdx.x & 63;
    int nw   = (gridDim.x * blockDim.x) >> 6;
    unsigned cnt = *count;
    for (unsigned w = wid; w < cnt; w += nw) {
        unsigned key = list[w];
        unsigned* v = out + (size_t)key * NCH;
        unsigned k = v[lane];
        v[lane] = (k == 0u) ? 0u : __float_as_uint(dec_key(k));
    }
}

extern "C" void kernel_launch(void* const* d_in, const int* in_sizes, int n_in,
                              void* d_out, int out_size, void* d_ws, size_t ws_size,
                              hipStream_t stream)
{
    const float* rois = (const float*)d_in[0];
    const float* pts  = (const float*)d_in[1];
    const float* feat = (const float*)d_in[2];
    int npts = in_sizes[1] / 3;

    unsigned* count = (unsigned*)d_ws;
    unsigned* flags = (unsigned*)((char*)d_ws + WS_FLAGS);
    unsigned* list  = (unsigned*)((char*)d_ws + WS_LIST);
    float4*   rej   = (float4*)((char*)d_ws + WS_REJ);
    float*    rad2  = (float*)((char*)d_ws + WS_RAD2);
    float*    full  = (float*)((char*)d_ws + WS_FULL);

    // Zero output accumulator (0u == empty == 0.0f bits) and count+flags.
    hipMemsetAsync(d_out, 0, (size_t)out_size * sizeof(float), stream);
    hipMemsetAsync(d_ws, 0, WS_FLAGS + (size_t)NKEYS * 4, stream);

    roi_prep<<<1, NROIS, 0, stream>>>(rois, rej, rad2, full);

    dim3 grid((npts + 255) / 256, NROIS / RPB);
    roi_pool_scatter<<<grid, 256, 0, stream>>>(pts, feat, rej, rad2, full,
                                               (unsigned*)d_out, count, flags,
                                               list, npts);

    decode_touched<<<256, 256, 0, stream>>>((unsigned*)d_out, count, list);
}

// Round 5
// 120.880 us; speedup vs baseline: 2.4833x; 2.4833x over previous
//
#include <hip/hip_runtime.h>

#define NROIS 128
#define OUTD  12
#define NVOX  (OUTD * OUTD * OUTD)
#define NCH   64
#define RPB   16                      // rois per block (grid.y = 8)
#define QCAP  1024                    // LDS hit-queue capacity (mean ~26/block)

// Order-preserving encode of float32 into uint32 for atomicMax.
// f >= 0 -> bits | 0x80000000 ; f < 0 -> ~bits. Encoded real floats are > 0,
// so key==0 marks "empty" (and equals the bit pattern of +0.0f).
__device__ __forceinline__ unsigned enc_f32(float f) {
    unsigned b = __float_as_uint(f);
    return (b & 0x80000000u) ? ~b : (b | 0x80000000u);
}

__device__ __forceinline__ float dec_key(unsigned k) {
    unsigned b = (k & 0x80000000u) ? (k & 0x7fffffffu) : ~k;
    return __uint_as_float(b);
}

// ws layout: float4 rej[128] | float rad2[128] | float4 full[128*3]
#define WS_REJ   0
#define WS_RAD2  (WS_REJ + NROIS * 16)
#define WS_FULL  (WS_RAD2 + NROIS * 4)

// Per-ROI precompute: exact reference-sequence params + conservative reject.
__global__ void roi_prep(const float* __restrict__ rois,
                         float4* __restrict__ rej, float* __restrict__ rad2,
                         float4* __restrict__ full)
{
    int r = threadIdx.x;
    if (r >= NROIS) return;
    float cx = rois[7 * r + 0];
    float cy = rois[7 * r + 1];
    float cz = rois[7 * r + 2];
    float dx = rois[7 * r + 3];
    float dy = rois[7 * r + 4];
    float dz = rois[7 * r + 5];
    float nrz = -rois[7 * r + 6];
    float ca = cosf(nrz), sa = sinf(nrz);
    float hx = __fmul_rn(dx, 0.5f);
    float hy = __fmul_rn(dy, 0.5f);
    float hz = __fmul_rn(dz, 0.5f);
    full[3 * r + 0] = make_float4(cx, cy, cz, ca);
    full[3 * r + 1] = make_float4(sa, hx, hy, hz);
    full[3 * r + 2] = make_float4(__fdiv_rn(dx, 12.0f), __fdiv_rn(dy, 12.0f),
                                  __fdiv_rn(dz, 12.0f), 0.0f);
    // Conservative superset reject: circle around (cx,cy) + z window.
    // Margins dwarf any fp-rounding difference vs the exact test.
    float R2 = 0.25f * (dx * dx + dy * dy);
    rad2[r] = R2 * 1.04f + 1e-4f;
    float zc = cz + hz;                 // z center of box
    float zh = hz * 1.001f + 1e-3f;     // half-height + ~3mm margin
    rej[r] = make_float4(cx, cy, zc, zh);
}

// grid = (ceil(P/256), NROIS/RPB). Point in registers, ROI loop over LDS
// params; hits are queued in LDS and drained wave-cooperatively (lane=channel)
// so the scatter tail is 2 coalesced VMEM instructions per hit instead of ~80
// divergent ones.
__global__ void __launch_bounds__(256) roi_pool_scatter(
        const float* __restrict__ pts,      // (P, 3)
        const float* __restrict__ feat,     // (P, 64)
        const float4* __restrict__ rej,
        const float* __restrict__ rad2,
        const float4* __restrict__ full,
        unsigned*    __restrict__ out,      // (128, 1728, 64) encoded keys
        int npts)
{
    __shared__ float4   sRej[RPB];
    __shared__ float    sRad[RPB];
    __shared__ float4   sFull[RPB * 3];
    __shared__ unsigned sQp[QCAP];
    __shared__ unsigned sQk[QCAP];
    __shared__ unsigned sQn;

    int rbase = blockIdx.y * RPB;
    if (threadIdx.x == 0) sQn = 0;
    if (threadIdx.x < RPB) {
        sRej[threadIdx.x] = rej[rbase + threadIdx.x];
        sRad[threadIdx.x] = rad2[rbase + threadIdx.x];
    }
    if (threadIdx.x < RPB * 3)
        sFull[threadIdx.x] = full[rbase * 3 + threadIdx.x];
    __syncthreads();

    int p = blockIdx.x * blockDim.x + threadIdx.x;
    if (p < npts) {
        float px = pts[3 * p + 0];
        float py = pts[3 * p + 1];
        float pz = pts[3 * p + 2];

        for (int r = 0; r < RPB; ++r) {
            // --- cheap conservative reject (wave-uniform LDS broadcast) ---
            float4 q = sRej[r];
            float sx = px - q.x;            // == __fsub_rn(px, cx)
            float sy = py - q.y;
            float d2 = sx * sx + sy * sy;   // contraction ok: margin absorbs
            if (!((d2 < sRad[r]) && (fabsf(pz - q.z) <= q.w))) continue;

            // --- exact reference test (reference float32 op sequence) ---
            float4 F0 = sFull[3 * r + 0];
            float4 F1 = sFull[3 * r + 1];
            float sz = __fsub_rn(pz, F0.z);
            float ca = F0.w, sa = F1.x;
            float hx = F1.y, hy = F1.z, hz = F1.w;
            float lx = __fsub_rn(__fmul_rn(sx, ca), __fmul_rn(sy, sa));
            float ly = __fadd_rn(__fmul_rn(sx, sa), __fmul_rn(sy, ca));

            bool in_box = (lx > -hx) && (lx < hx) &&
                          (ly > -hy) && (ly < hy) &&
                          (fabsf(__fsub_rn(sz, hz)) <= hz);
            if (!in_box) continue;

            float4 F2 = sFull[3 * r + 2];
            int xi = (int)floorf(__fdiv_rn(__fadd_rn(lx, hx), F2.x));
            int yi = (int)floorf(__fdiv_rn(__fadd_rn(ly, hy), F2.y));
            int zi = (int)floorf(__fdiv_rn(sz,                F2.z));
            xi = min(max(xi, 0), OUTD - 1);
            yi = min(max(yi, 0), OUTD - 1);
            zi = min(max(zi, 0), OUTD - 1);

            unsigned key = (unsigned)((rbase + r) * NVOX +
                                      xi * (OUTD * OUTD) + yi * OUTD + zi);

            unsigned idx = atomicAdd(&sQn, 1u);
            if (idx < QCAP) {
                sQp[idx] = (unsigned)p;
                sQk[idx] = key;
            } else {
                // Overflow fallback (statistically never: mean 26/block).
                unsigned* dst = out + (size_t)key * NCH;
                const float* fp = feat + (size_t)p * NCH;
                #pragma unroll 1
                for (int c = 0; c < NCH; ++c)
                    atomicMax(dst + c, enc_f32(fp[c]));
            }
        }
    }

    __syncthreads();
    // Wave-cooperative drain: one queue entry per wave, lane = channel.
    // One coalesced 256B load + one coalesced 256B atomic per hit.
    int nq   = min((int)sQn, QCAP);
    int wid  = threadIdx.x >> 6;
    int lane = threadIdx.x & 63;
    for (int i = wid; i < nq; i += 4) {
        unsigned pp = sQp[i];
        unsigned kk = sQk[i];
        float f = feat[(size_t)pp * NCH + lane];
        atomicMax(out + (size_t)kk * NCH + lane, enc_f32(f));
    }
}

// Full-buffer decode; empty voxels (key 0u == 0.0f bits) skip the store.
__global__ void __launch_bounds__(256) decode_keys(unsigned* __restrict__ out, int n4)
{
    int i = blockIdx.x * blockDim.x + threadIdx.x;
    if (i >= n4) return;
    uint4 k = reinterpret_cast<uint4*>(out)[i];
    if ((k.x | k.y | k.z | k.w) == 0u) return;
    float4 f;
    f.x = (k.x == 0u) ? 0.0f : dec_key(k.x);
    f.y = (k.y == 0u) ? 0.0f : dec_key(k.y);
    f.z = (k.z == 0u) ? 0.0f : dec_key(k.z);
    f.w = (k.w == 0u) ? 0.0f : dec_key(k.w);
    reinterpret_cast<float4*>(out)[i] = f;
}

extern "C" void kernel_launch(void* const* d_in, const int* in_sizes, int n_in,
                              void* d_out, int out_size, void* d_ws, size_t ws_size,
                              hipStream_t stream)
{
    const float* rois = (const float*)d_in[0];
    const float* pts  = (const float*)d_in[1];
    const float* feat = (const float*)d_in[2];
    int npts = in_sizes[1] / 3;

    float4* rej  = (float4*)((char*)d_ws + WS_REJ);
    float*  rad2 = (float*)((char*)d_ws + WS_RAD2);
    float4* full = (float4*)((char*)d_ws + WS_FULL);

    // Zero output accumulator (0u == empty == 0.0f bits).
    hipMemsetAsync(d_out, 0, (size_t)out_size * sizeof(float), stream);

    roi_prep<<<1, NROIS, 0, stream>>>(rois, rej, rad2, full);

    dim3 grid((npts + 255) / 256, NROIS / RPB);
    roi_pool_scatter<<<grid, 256, 0, stream>>>(pts, feat, rej, rad2, full,
                                               (unsigned*)d_out, npts);

    int n4 = out_size / 4;
    decode_keys<<<(n4 + 255) / 256, 256, 0, stream>>>((unsigned*)d_out, n4);
}

// Round 6
// 117.745 us; speedup vs baseline: 2.5494x; 1.0266x over previous
//
#include <hip/hip_runtime.h>

#define NROIS 128
#define OUTD  12
#define NVOX  (OUTD * OUTD * OUTD)
#define NCH   64
#define NKEYS (NROIS * NVOX)          // 221184 (roi,voxel) keys
#define NWORDS (NKEYS / 32)           // 6912 bitmask words
#define RPB   16                      // rois per block (grid.y = 8)
#define QCAP  1024                    // LDS hit-queue capacity (mean ~26/block)

// Order-preserving encode of float32 into uint32 for atomicMax.
// f >= 0 -> bits | 0x80000000 ; f < 0 -> ~bits. Encoded real floats are > 0,
// so key==0 marks "empty" (and equals the bit pattern of +0.0f).
__device__ __forceinline__ unsigned enc_f32(float f) {
    unsigned b = __float_as_uint(f);
    return (b & 0x80000000u) ? ~b : (b | 0x80000000u);
}

__device__ __forceinline__ float dec_key(unsigned k) {
    unsigned b = (k & 0x80000000u) ? (k & 0x7fffffffu) : ~k;
    return __uint_as_float(b);
}

// grid = (ceil(P/256), NROIS/RPB). ROI prep fused per-block (lanes 0..RPB-1),
// point in registers, ROI loop over LDS params. Hits are queued in LDS and
// drained wave-cooperatively (lane = channel): one coalesced 256B load + one
// coalesced 256B atomic per hit, plus a fire-and-forget atomicOr into the
// touched-voxel bitmask for the sparse decode pass.
__global__ void __launch_bounds__(256) roi_pool_scatter(
        const float* __restrict__ rois,     // (128, 7)
        const float* __restrict__ pts,      // (P, 3)
        const float* __restrict__ feat,     // (P, 64)
        unsigned*    __restrict__ out,      // (128, 1728, 64) encoded keys
        unsigned*    __restrict__ mask,     // bitmask[NWORDS] of touched voxels
        int npts)
{
    __shared__ float4   sRej[RPB];      // cx, cy, zc, zh
    __shared__ float    sRad[RPB];      // conservative radius^2
    __shared__ float4   sFull[RPB * 3];
    __shared__ unsigned sQp[QCAP];
    __shared__ unsigned sQk[QCAP];
    __shared__ unsigned sQn;

    int rbase = blockIdx.y * RPB;
    if (threadIdx.x == 0) sQn = 0;
    if (threadIdx.x < RPB) {
        int r = rbase + threadIdx.x;
        // Exact reference-sequence params (bit-identical to prior roi_prep).
        float cx = rois[7 * r + 0];
        float cy = rois[7 * r + 1];
        float cz = rois[7 * r + 2];
        float dx = rois[7 * r + 3];
        float dy = rois[7 * r + 4];
        float dz = rois[7 * r + 5];
        float nrz = -rois[7 * r + 6];
        float ca = cosf(nrz), sa = sinf(nrz);
        float hx = __fmul_rn(dx, 0.5f);
        float hy = __fmul_rn(dy, 0.5f);
        float hz = __fmul_rn(dz, 0.5f);
        sFull[3 * threadIdx.x + 0] = make_float4(cx, cy, cz, ca);
        sFull[3 * threadIdx.x + 1] = make_float4(sa, hx, hy, hz);
        sFull[3 * threadIdx.x + 2] = make_float4(__fdiv_rn(dx, 12.0f),
                                                 __fdiv_rn(dy, 12.0f),
                                                 __fdiv_rn(dz, 12.0f), 0.0f);
        // Conservative superset reject: circle + z window, margins dwarf
        // any fp-rounding difference vs the exact test.
        float R2 = 0.25f * (dx * dx + dy * dy);
        sRad[threadIdx.x] = R2 * 1.04f + 1e-4f;
        sRej[threadIdx.x] = make_float4(cx, cy, cz + hz, hz * 1.001f + 1e-3f);
    }
    __syncthreads();

    int p = blockIdx.x * blockDim.x + threadIdx.x;
    if (p < npts) {
        float px = pts[3 * p + 0];
        float py = pts[3 * p + 1];
        float pz = pts[3 * p + 2];

        for (int r = 0; r < RPB; ++r) {
            // --- cheap conservative reject ---
            float4 q = sRej[r];
            float sx = px - q.x;            // == __fsub_rn(px, cx)
            float sy = py - q.y;
            float d2 = sx * sx + sy * sy;   // contraction ok: margin absorbs
            if (!((d2 < sRad[r]) && (fabsf(pz - q.z) <= q.w))) continue;

            // --- exact reference test (reference float32 op sequence) ---
            float4 F0 = sFull[3 * r + 0];
            float4 F1 = sFull[3 * r + 1];
            float sz = __fsub_rn(pz, F0.z);
            float ca = F0.w, sa = F1.x;
            float hx = F1.y, hy = F1.z, hz = F1.w;
            float lx = __fsub_rn(__fmul_rn(sx, ca), __fmul_rn(sy, sa));
            float ly = __fadd_rn(__fmul_rn(sx, sa), __fmul_rn(sy, ca));

            bool in_box = (lx > -hx) && (lx < hx) &&
                          (ly > -hy) && (ly < hy) &&
                          (fabsf(__fsub_rn(sz, hz)) <= hz);
            if (!in_box) continue;

            float4 F2 = sFull[3 * r + 2];
            int xi = (int)floorf(__fdiv_rn(__fadd_rn(lx, hx), F2.x));
            int yi = (int)floorf(__fdiv_rn(__fadd_rn(ly, hy), F2.y));
            int zi = (int)floorf(__fdiv_rn(sz,                F2.z));
            xi = min(max(xi, 0), OUTD - 1);
            yi = min(max(yi, 0), OUTD - 1);
            zi = min(max(zi, 0), OUTD - 1);

            unsigned key = (unsigned)((rbase + r) * NVOX +
                                      xi * (OUTD * OUTD) + yi * OUTD + zi);

            unsigned idx = atomicAdd(&sQn, 1u);
            if (idx < QCAP) {
                sQp[idx] = (unsigned)p;
                sQk[idx] = key;
            } else {
                // Overflow fallback (statistically never: mean ~26/block).
                atomicOr(&mask[key >> 5], 1u << (key & 31));
                unsigned* dst = out + (size_t)key * NCH;
                const float* fp = feat + (size_t)p * NCH;
                #pragma unroll 1
                for (int c = 0; c < NCH; ++c)
                    atomicMax(dst + c, enc_f32(fp[c]));
            }
        }
    }

    __syncthreads();
    // Wave-cooperative drain: one queue entry per wave, lane = channel.
    int nq   = min((int)sQn, QCAP);
    int wid  = threadIdx.x >> 6;
    int lane = threadIdx.x & 63;
    for (int i = wid; i < nq; i += 4) {
        unsigned pp = sQp[i];
        unsigned kk = sQk[i];
        if (lane == 0)                      // fire-and-forget, no return value
            atomicOr(&mask[kk >> 5], 1u << (kk & 31));
        float f = feat[(size_t)pp * NCH + lane];
        atomicMax(out + (size_t)kk * NCH + lane, enc_f32(f));
    }
}

// Sparse decode: one wave per bitmask word; set bits -> decode that voxel's
// 64 channels (lane = channel). Untouched voxels keep memset's 0u == 0.0f.
__global__ void __launch_bounds__(256) decode_touched(
        unsigned* __restrict__ out,
        const unsigned* __restrict__ mask)
{
    int w    = (blockIdx.x * blockDim.x + threadIdx.x) >> 6;
    int lane = threadIdx.x & 63;
    if (w >= NWORDS) return;
    unsigned word = mask[w];
    while (word) {
        int bit = __ffs(word) - 1;
        word &= word - 1;
        unsigned key = (unsigned)(w * 32 + bit);
        unsigned* v = out + (size_t)key * NCH;
        unsigned k = v[lane];
        v[lane] = (k == 0u) ? 0u : __float_as_uint(dec_key(k));
    }
}

extern "C" void kernel_launch(void* const* d_in, const int* in_sizes, int n_in,
                              void* d_out, int out_size, void* d_ws, size_t ws_size,
                              hipStream_t stream)
{
    const float* rois = (const float*)d_in[0];
    const float* pts  = (const float*)d_in[1];
    const float* feat = (const float*)d_in[2];
    int npts = in_sizes[1] / 3;

    unsigned* mask = (unsigned*)d_ws;   // NWORDS u32 = 27.6 KB

    // Zero output accumulator (0u == empty == 0.0f bits) and the bitmask.
    hipMemsetAsync(d_out, 0, (size_t)out_size * sizeof(float), stream);
    hipMemsetAsync(d_ws, 0, NWORDS * sizeof(unsigned), stream);

    dim3 grid((npts + 255) / 256, NROIS / RPB);
    roi_pool_scatter<<<grid, 256, 0, stream>>>(rois, pts, feat,
                                               (unsigned*)d_out, mask, npts);

    decode_touched<<<NWORDS / 4, 256, 0, stream>>>((unsigned*)d_out, mask);
}

// Round 7
// 114.670 us; speedup vs baseline: 2.6177x; 1.0268x over previous
//
#include <hip/hip_runtime.h>

#define NROIS 128
#define OUTD  12
#define NVOX  (OUTD * OUTD * OUTD)
#define NCH   64
#define NKEYS (NROIS * NVOX)          // 221184 (roi,voxel) keys
#define RPB   16                      // rois per block (grid.y = 8)
#define QCAP  1024                    // LDS hit-queue capacity (mean ~26/block)
#define STAMP 0x5AFE5AFEu             // != 0, != 0xAAAAAAAA harness poison

// Order-preserving encode of float32 into uint32 for atomicMax.
// f >= 0 -> bits | 0x80000000 ; f < 0 -> ~bits. Encoded real floats are > 0,
// so key==0 marks "empty" (and equals the bit pattern of +0.0f).
__device__ __forceinline__ unsigned enc_f32(float f) {
    unsigned b = __float_as_uint(f);
    return (b & 0x80000000u) ? ~b : (b | 0x80000000u);
}

__device__ __forceinline__ float dec_key(unsigned k) {
    unsigned b = (k & 0x80000000u) ? (k & 0x7fffffffu) : ~k;
    return __uint_as_float(b);
}

// grid = (ceil(P/256), NROIS/RPB). Per-block fused ROI prep, point in
// registers. Hot loop is a BRANCHLESS conservative-reject sweep building a
// 16-bit hitmask (compiler can batch all LDS reads -> one lgkmcnt wait);
// the exact reference test runs only on surviving (lane,roi) pairs. Hits are
// queued in LDS and drained wave-cooperatively (lane = channel): one
// coalesced 256B load + one coalesced 256B atomic per hit, plus an
// idempotent stamp store marking the voxel touched for the decode pass.
__global__ void __launch_bounds__(256) roi_pool_scatter(
        const float* __restrict__ rois,     // (128, 7)
        const float* __restrict__ pts,      // (P, 3)
        const float* __restrict__ feat,     // (P, 64)
        unsigned*    __restrict__ out,      // (128, 1728, 64) encoded keys
        unsigned*    __restrict__ stamp,    // u32[NKEYS] touched markers
        int npts)
{
    __shared__ float4   sRej[RPB];      // cx, cy, zc, zh
    __shared__ float    sRad[RPB];      // conservative radius^2
    __shared__ float4   sFull[RPB * 3];
    __shared__ unsigned sQp[QCAP];
    __shared__ unsigned sQk[QCAP];
    __shared__ unsigned sQn;

    int rbase = blockIdx.y * RPB;
    if (threadIdx.x == 0) sQn = 0;
    if (threadIdx.x < RPB) {
        int r = rbase + threadIdx.x;
        // Exact reference-sequence params (bit-identical to the reference).
        float cx = rois[7 * r + 0];
        float cy = rois[7 * r + 1];
        float cz = rois[7 * r + 2];
        float dx = rois[7 * r + 3];
        float dy = rois[7 * r + 4];
        float dz = rois[7 * r + 5];
        float nrz = -rois[7 * r + 6];
        float ca = cosf(nrz), sa = sinf(nrz);
        float hx = __fmul_rn(dx, 0.5f);
        float hy = __fmul_rn(dy, 0.5f);
        float hz = __fmul_rn(dz, 0.5f);
        sFull[3 * threadIdx.x + 0] = make_float4(cx, cy, cz, ca);
        sFull[3 * threadIdx.x + 1] = make_float4(sa, hx, hy, hz);
        sFull[3 * threadIdx.x + 2] = make_float4(__fdiv_rn(dx, 12.0f),
                                                 __fdiv_rn(dy, 12.0f),
                                                 __fdiv_rn(dz, 12.0f), 0.0f);
        // Conservative superset reject (circle + z window); margins dwarf
        // any fp-rounding difference vs the exact test.
        float R2 = 0.25f * (dx * dx + dy * dy);
        sRad[threadIdx.x] = R2 * 1.04f + 1e-4f;
        sRej[threadIdx.x] = make_float4(cx, cy, cz + hz, hz * 1.001f + 1e-3f);
    }
    __syncthreads();

    int p = blockIdx.x * blockDim.x + threadIdx.x;
    if (p < npts) {
        float px = pts[3 * p + 0];
        float py = pts[3 * p + 1];
        float pz = pts[3 * p + 2];

        // --- branchless reject sweep over all RPB rois ---
        unsigned hm = 0;
        #pragma unroll
        for (int r = 0; r < RPB; ++r) {
            float4 q = sRej[r];
            float sx = px - q.x;
            float sy = py - q.y;
            float d2 = sx * sx + sy * sy;   // contraction ok: margin absorbs
            bool maybe = (d2 < sRad[r]) & (fabsf(pz - q.z) <= q.w);
            hm |= ((unsigned)maybe) << r;
        }

        // --- rare path: exact reference test per surviving roi ---
        while (hm) {
            int r = __ffs(hm) - 1;
            hm &= hm - 1;
            float4 F0 = sFull[3 * r + 0];
            float4 F1 = sFull[3 * r + 1];
            float sx = __fsub_rn(px, F0.x);
            float sy = __fsub_rn(py, F0.y);
            float sz = __fsub_rn(pz, F0.z);
            float ca = F0.w, sa = F1.x;
            float hx = F1.y, hy = F1.z, hz = F1.w;
            float lx = __fsub_rn(__fmul_rn(sx, ca), __fmul_rn(sy, sa));
            float ly = __fadd_rn(__fmul_rn(sx, sa), __fmul_rn(sy, ca));

            bool in_box = (lx > -hx) && (lx < hx) &&
                          (ly > -hy) && (ly < hy) &&
                          (fabsf(__fsub_rn(sz, hz)) <= hz);
            if (!in_box) continue;

            float4 F2 = sFull[3 * r + 2];
            int xi = (int)floorf(__fdiv_rn(__fadd_rn(lx, hx), F2.x));
            int yi = (int)floorf(__fdiv_rn(__fadd_rn(ly, hy), F2.y));
            int zi = (int)floorf(__fdiv_rn(sz,                F2.z));
            xi = min(max(xi, 0), OUTD - 1);
            yi = min(max(yi, 0), OUTD - 1);
            zi = min(max(zi, 0), OUTD - 1);

            unsigned key = (unsigned)((rbase + r) * NVOX +
                                      xi * (OUTD * OUTD) + yi * OUTD + zi);

            unsigned idx = atomicAdd(&sQn, 1u);
            if (idx < QCAP) {
                sQp[idx] = (unsigned)p;
                sQk[idx] = key;
            } else {
                // Overflow fallback (statistically never: mean ~26/block).
                stamp[key] = STAMP;
                unsigned* dst = out + (size_t)key * NCH;
                const float* fp = feat + (size_t)p * NCH;
                #pragma unroll 1
                for (int c = 0; c < NCH; ++c)
                    atomicMax(dst + c, enc_f32(fp[c]));
            }
        }
    }

    __syncthreads();
    // Wave-cooperative drain: one queue entry per wave, lane = channel.
    int nq   = min((int)sQn, QCAP);
    int wid  = threadIdx.x >> 6;
    int lane = threadIdx.x & 63;
    for (int i = wid; i < nq; i += 4) {
        unsigned pp = sQp[i];
        unsigned kk = sQk[i];
        if (lane == 0) stamp[kk] = STAMP;   // idempotent, fire-and-forget
        float f = feat[(size_t)pp * NCH + lane];
        atomicMax(out + (size_t)kk * NCH + lane, enc_f32(f));
    }
}

// Sparse decode: one wave per 64 keys. Lane i checks stamp[base+i]; ballot
// gives the touched set; each touched key's 64 channels are decoded with
// lane = channel. Untouched voxels keep memset's 0u == 0.0f bits.
__global__ void __launch_bounds__(256) decode_touched(
        unsigned* __restrict__ out,
        const unsigned* __restrict__ stamp)
{
    int w    = (blockIdx.x * blockDim.x + threadIdx.x) >> 6;
    int lane = threadIdx.x & 63;
    int base = w * 64;
    if (base >= NKEYS) return;
    unsigned s = stamp[base + lane];
    unsigned long long m = __ballot(s == STAMP);
    while (m) {
        int b = __ffsll((long long)m) - 1;
        m &= m - 1;
        unsigned key = (unsigned)(base + b);
        unsigned* v = out + (size_t)key * NCH;
        unsigned k = v[lane];
        v[lane] = (k == 0u) ? 0u : __float_as_uint(dec_key(k));
    }
}

extern "C" void kernel_launch(void* const* d_in, const int* in_sizes, int n_in,
                              void* d_out, int out_size, void* d_ws, size_t ws_size,
                              hipStream_t stream)
{
    const float* rois = (const float*)d_in[0];
    const float* pts  = (const float*)d_in[1];
    const float* feat = (const float*)d_in[2];
    int npts = in_sizes[1] / 3;

    unsigned* stamp = (unsigned*)d_ws;  // NKEYS u32 = 884 KB (poison != STAMP)

    // Zero output accumulator (0u == empty == 0.0f bits). No stamp memset
    // needed: harness poison 0xAAAAAAAA != STAMP.
    hipMemsetAsync(d_out, 0, (size_t)out_size * sizeof(float), stream);

    dim3 grid((npts + 255) / 256, NROIS / RPB);
    roi_pool_scatter<<<grid, 256, 0, stream>>>(rois, pts, feat,
                                               (unsigned*)d_out, stamp, npts);

    // NKEYS/64 waves, 4 waves per block.
    decode_touched<<<NKEYS / 256, 256, 0, stream>>>((unsigned*)d_out, stamp);
}